// Round 3
// baseline (3776.678 us; speedup 1.0000x reference)
//
#include <hip/hip_runtime.h>
#include <hip/hip_bf16.h>

#define B_ 4
#define N_ 4096
#define C_ 256
#define D_ 32
#define LOG2E 1.44269504088896340736f

typedef __attribute__((ext_vector_type(8))) short short8;   // 8 x bf16 (4 VGPRs)
typedef __attribute__((ext_vector_type(4))) short short4v;  // 4 x bf16 (8 B)
typedef __attribute__((ext_vector_type(4))) float float4v;  // MFMA C/D frag

// cheap round-to-nearest-even fp32->bf16 (finite inputs only): 3 VALU ops
__device__ inline short f2bf_rne(float f) {
  unsigned u = __builtin_bit_cast(unsigned, f);
  u += 0x7FFFu + ((u >> 16) & 1u);
  return (short)(u >> 16);
}

__device__ inline float fast_exp2(float x) { return __builtin_amdgcn_exp2f(x); }

// ---------------------------------------------------------------------------
// Kernel 1: build fragment-linearized bf16 weights WtF.
// Frag f = nb*8+ks (nb 0..19, ks 0..7). Element (f, lane l, j) = W[k][n],
//   n = nb*16 + (l&15), k = ks*32 + (l>>4)*8 + j.
// So proj's B-frag load is one lane-contiguous 16B read: WtF + f*512 + l*8.
// log2(e) folded into the Wq columns (n<32).
// ---------------------------------------------------------------------------
__global__ __launch_bounds__(256) void cast_w_kernel(
    const float* __restrict__ Wq, const float* __restrict__ Wk,
    const float* __restrict__ Wv, short* __restrict__ WtF) {
  int i  = blockIdx.x * 256 + threadIdx.x;  // 0..81919
  int j  = i & 7;
  int l  = (i >> 3) & 63;
  int ks = (i >> 9) & 7;
  int nb = i >> 12;
  int n  = nb * 16 + (l & 15);
  int k  = ks * 32 + ((l >> 4) << 3) + j;
  float v;
  if (n < 32)      v = Wq[k * 32 + n] * LOG2E;
  else if (n < 64) v = Wk[k * 32 + (n - 32)];
  else             v = Wv[k * 256 + (n - 64)];
  WtF[i] = f2bf_rne(v);
}

// ---------------------------------------------------------------------------
// Kernel 2: fused QKV projection. 512 blocks x 256 thr (2 blocks/CU),
// 32 pixel rows per block. x staged to LDS once; W B-frags are single
// coalesced 16B loads from fragment-linear WtF (L2-resident, no barriers in
// the MFMA loop). V output transposed through LDS -> full-line vT stores.
// ---------------------------------------------------------------------------
__global__ __launch_bounds__(256, 2) void proj_kernel(
    const float* __restrict__ x, const short* __restrict__ WtF,
    const float* __restrict__ bq, const float* __restrict__ bk,
    const float* __restrict__ bv,
    short* __restrict__ qb, short* __restrict__ kb2, short* __restrict__ vT) {
  int blk = blockIdx.x;
  int b  = blk >> 7;
  int r0 = (blk & 127) * 32;
  int t  = threadIdx.x;
  int w  = t >> 6;
  int l  = t & 63;
  int lc = l & 15;
  int q4 = l >> 4;

  __shared__ __align__(16) short sA[32][272];  // 32 rows x 256 k (+16 pad) 17.4 KB
  __shared__ __align__(16) short sV[256][40];  // c x 32 rows (+8 pad)      20.5 KB

  // stage x tile (fp32 -> bf16), once
  {
    int row = t >> 3;
    int c0  = (t & 7) * 32;
    const float* src = x + (size_t)(b * N_ + r0 + row) * C_ + c0;
#pragma unroll
    for (int i = 0; i < 4; i++) {
      float4v v0 = *(const float4v*)(src + i * 8);
      float4v v1 = *(const float4v*)(src + i * 8 + 4);
      short8 s;
      s[0] = f2bf_rne(v0[0]); s[1] = f2bf_rne(v0[1]); s[2] = f2bf_rne(v0[2]); s[3] = f2bf_rne(v0[3]);
      s[4] = f2bf_rne(v1[0]); s[5] = f2bf_rne(v1[1]); s[6] = f2bf_rne(v1[2]); s[7] = f2bf_rne(v1[3]);
      *(short8*)(&sA[row][c0 + i * 8]) = s;
    }
  }
  __syncthreads();

  float4v acc[10];  // [nbo*2 + rt]
#pragma unroll
  for (int i = 0; i < 10; i++) { acc[i][0] = 0.f; acc[i][1] = 0.f; acc[i][2] = 0.f; acc[i][3] = 0.f; }

#pragma unroll
  for (int ks = 0; ks < 8; ks++) {
    short8 af0 = *(const short8*)(&sA[lc][ks * 32 + q4 * 8]);
    short8 af1 = *(const short8*)(&sA[16 + lc][ks * 32 + q4 * 8]);
#pragma unroll
    for (int nbo = 0; nbo < 5; nbo++) {
      int nb = w * 5 + nbo;
      short8 bf = *(const short8*)(WtF + (((nb << 3) + ks) << 9) + l * 8);
      acc[nbo * 2 + 0] = __builtin_amdgcn_mfma_f32_16x16x32_bf16(af0, bf, acc[nbo * 2 + 0], 0, 0, 0);
      acc[nbo * 2 + 1] = __builtin_amdgcn_mfma_f32_16x16x32_bf16(af1, bf, acc[nbo * 2 + 1], 0, 0, 0);
    }
  }

  // epilogue: bias, cast; q/k direct, v -> LDS transpose
#pragma unroll
  for (int nbo = 0; nbo < 5; nbo++) {
    int n = (w * 5 + nbo) * 16 + lc;
    float bias = (n < 32) ? bq[n] * LOG2E : (n < 64) ? bk[n - 32] : bv[n - 64];
#pragma unroll
    for (int rt = 0; rt < 2; rt++) {
#pragma unroll
      for (int r = 0; r < 4; r++) {
        int row = rt * 16 + q4 * 4 + r;  // C-layout: row=(lane>>4)*4+reg
        short s = f2bf_rne(acc[nbo * 2 + rt][r] + bias);
        if (n < 32)      qb [(size_t)(b * N_ + r0 + row) * D_ + n] = s;
        else if (n < 64) kb2[(size_t)(b * N_ + r0 + row) * D_ + (n - 32)] = s;
        else             sV[n - 64][row] = s;
      }
    }
  }
  __syncthreads();

  // vT store: thread t owns channel c=t, writes 32 rows = 64 B (one full line)
  {
    int c = t;
    short8 v0 = *(const short8*)(&sV[c][0]);
    short8 v1 = *(const short8*)(&sV[c][8]);
    short8 v2 = *(const short8*)(&sV[c][16]);
    short8 v3 = *(const short8*)(&sV[c][24]);
    short* dst = vT + (size_t)(b * C_ + c) * N_ + r0;
    *(short8*)(dst)      = v0;
    *(short8*)(dst + 8)  = v1;
    *(short8*)(dst + 16) = v2;
    *(short8*)(dst + 24) = v3;
  }
}

// ---------------------------------------------------------------------------
// Kernel 3: flash attention (fixed-max exp2-domain) + gamma*out + residual.
// 256 blocks x 512 thr (8 waves -> 2 waves/SIMD). Wave specialization:
//   waves 0-3: QK (own 16-row tile) + softmax + sP write, plus PV slice.
//   waves 4-7: PV slice only.
// Every wave owns 32 output channels. K/V frags direct global->VGPR,
// double-buffered registers, prefetch issued at loop TOP so the pre-barrier
// vmcnt(0) drain overlaps ~300 cyc of softmax compute.
// ---------------------------------------------------------------------------
__global__ __launch_bounds__(512, 2) void flash_kernel(
    const short* __restrict__ qb, const short* __restrict__ kb,
    const short* __restrict__ vT, const float* __restrict__ xin,
    const float* __restrict__ gptr, float* __restrict__ out) {
  int blk = blockIdx.x;
  int b  = blk & 3;                            // XCD (blk%8) -> single batch
  int qt = (blk >> 3) * 2 + ((blk >> 2) & 1);  // bijective over 0..63 per batch
  int r0 = qt * 64;
  int t  = threadIdx.x;
  int w  = t >> 6;                             // 0..7
  int l  = t & 63;
  int lc = l & 15;
  int q4 = l >> 4;

  __shared__ __align__(16) short sP[2][64][80];  // dbuf P, stride 80 (20.5 KB)
  __shared__ float sL[64];

  const short* kbase = kb + (size_t)b * N_ * D_;
  const short* vbase = vT + (size_t)b * C_ * N_;

  bool qkwave = (w < 4);
  int rq = w & 3;           // QK rowtile for waves 0-3
  int chbase = w * 32;      // PV channel slice, all 8 waves

  // Q as B-frag (B[k=d][n=qrow]); log2e already folded into weights
  short8 qf = *(const short8*)(qb + (size_t)(b * N_ + r0 + rq * 16 + lc) * D_ + q4 * 8);

  const short* kp = kbase + lc * D_ + q4 * 8;
  const short* vp = vbase + (size_t)(chbase + lc) * N_ + q4 * 8;

  short8 kreg[2][4];   // K A-frags, double-buffered
  short8 vreg[2][4];   // V B-frags [cb*2+ks], double-buffered
#pragma unroll
  for (int i = 0; i < 4; i++) kreg[0][i] = *(const short8*)(kp + i * 16 * D_);
#pragma unroll
  for (int cb = 0; cb < 2; cb++)
#pragma unroll
    for (int ks = 0; ks < 2; ks++)
      vreg[0][cb * 2 + ks] = *(const short8*)(vp + (size_t)cb * 16 * N_ + ks * 32);

  float4v O[8];  // [rt*2 + cb]
#pragma unroll
  for (int i = 0; i < 8; i++) { O[i][0] = 0.f; O[i][1] = 0.f; O[i][2] = 0.f; O[i][3] = 0.f; }
  float l_part = 0.f;

  for (int kt = 0; kt < 64; kt++) {
    int cur = kt & 1, nxt = cur ^ 1;
    int nkt = (kt < 63) ? kt + 1 : 63;  // branchless tail

    // ---- prefetch next tile FIRST (max distance to the barrier drain) ----
    if (qkwave) {
#pragma unroll
      for (int i = 0; i < 4; i++)
        kreg[nxt][i] = *(const short8*)(kp + (size_t)nkt * 64 * D_ + i * 16 * D_);
    }
#pragma unroll
    for (int cb = 0; cb < 2; cb++)
#pragma unroll
      for (int ks = 0; ks < 2; ks++)
        vreg[nxt][cb * 2 + ks] =
            *(const short8*)(vp + (size_t)cb * 16 * N_ + (size_t)nkt * 64 + ks * 32);

    // ---- waves 0-3: St = K*Q^T, softmax numerators, sP write ----
    if (qkwave) {
      float4v St[4];
#pragma unroll
      for (int i = 0; i < 4; i++) {
        float4v z; z[0] = 0.f; z[1] = 0.f; z[2] = 0.f; z[3] = 0.f;
        St[i] = __builtin_amdgcn_mfma_f32_16x16x32_bf16(kreg[cur][i], qf, z, 0, 0, 0);
      }
      float tilesum = 0.f;
#pragma unroll
      for (int i = 0; i < 4; i++) {
        float p0 = fast_exp2(St[i][0]);
        float p1 = fast_exp2(St[i][1]);
        float p2 = fast_exp2(St[i][2]);
        float p3 = fast_exp2(St[i][3]);
        tilesum += (p0 + p1) + (p2 + p3);
        short4v pk;
        pk[0] = f2bf_rne(p0); pk[1] = f2bf_rne(p1); pk[2] = f2bf_rne(p2); pk[3] = f2bf_rne(p3);
        *(short4v*)(&sP[cur][rq * 16 + lc][i * 16 + q4 * 4]) = pk;
      }
      l_part += tilesum;
    }

    __syncthreads();

    // ---- all waves: P A-frags from LDS, PV into O ----
    short8 pf[8];
#pragma unroll
    for (int rt = 0; rt < 4; rt++)
#pragma unroll
      for (int ks = 0; ks < 2; ks++)
        pf[rt * 2 + ks] = *(const short8*)(&sP[cur][rt * 16 + lc][ks * 32 + q4 * 8]);

#pragma unroll
    for (int rt = 0; rt < 4; rt++)
#pragma unroll
      for (int cb = 0; cb < 2; cb++)
#pragma unroll
        for (int ks = 0; ks < 2; ks++)
          O[rt * 2 + cb] = __builtin_amdgcn_mfma_f32_16x16x32_bf16(
              pf[rt * 2 + ks], vreg[cur][cb * 2 + ks], O[rt * 2 + cb], 0, 0, 0);
  }

  // denominator: per-lane partials cover qrow=lc, kv in this lane's groups;
  // reduce across the 4 q4 groups
  if (qkwave) {
    float l_tot = l_part + __shfl_xor(l_part, 16, 64);
    l_tot += __shfl_xor(l_tot, 32, 64);
    sL[rq * 16 + lc] = l_tot;
  }
  __syncthreads();

  float g = *gptr;
#pragma unroll
  for (int rt = 0; rt < 4; rt++) {
    float4v lv = *(const float4v*)(&sL[rt * 16 + q4 * 4]);
    float4v inv;
#pragma unroll
    for (int r = 0; r < 4; r++) inv[r] = __builtin_amdgcn_rcpf(lv[r]);
#pragma unroll
    for (int cb = 0; cb < 2; cb++) {
#pragma unroll
      for (int r = 0; r < 4; r++) {
        size_t idx = (size_t)(b * N_ + r0 + rt * 16 + q4 * 4 + r) * C_ + chbase + cb * 16 + lc;
        out[idx] = g * (O[rt * 2 + cb][r] * inv[r]) + xin[idx];
      }
    }
  }
}

// ---------------------------------------------------------------------------
extern "C" void kernel_launch(void* const* d_in, const int* in_sizes, int n_in,
                              void* d_out, int out_size, void* d_ws, size_t ws_size,
                              hipStream_t stream) {
  const float* x     = (const float*)d_in[0];
  const float* Wq    = (const float*)d_in[1];
  const float* bq    = (const float*)d_in[2];
  const float* Wk    = (const float*)d_in[3];
  const float* bk    = (const float*)d_in[4];
  const float* Wv    = (const float*)d_in[5];
  const float* bv    = (const float*)d_in[6];
  const float* gamma = (const float*)d_in[7];
  float* out = (float*)d_out;

  char* ws = (char*)d_ws;
  short* qb  = (short*)ws;                   // B*N*D bf16  = 1 MB
  short* kb  = (short*)(ws + (1u << 20));    // B*N*D bf16  = 1 MB
  short* vT  = (short*)(ws + (2u << 20));    // B*C*N bf16  = 8 MB (channel-major)
  short* WtF = (short*)(ws + (10u << 20));   // 81920 bf16 fragment-linear = 160 KB

  hipLaunchKernelGGL(cast_w_kernel, dim3(320), dim3(256), 0, stream, Wq, Wk, Wv, WtF);
  hipLaunchKernelGGL(proj_kernel,   dim3(512), dim3(256), 0, stream, x, WtF, bq, bk, bv, qb, kb, vT);
  hipLaunchKernelGGL(flash_kernel,  dim3(256), dim3(512), 0, stream, qb, kb, vT, x, gamma, out);
}

// Round 4
// 171.277 us; speedup vs baseline: 22.0502x; 22.0502x over previous
//
#include <hip/hip_runtime.h>
#include <hip/hip_bf16.h>

#define B_ 4
#define N_ 4096
#define C_ 256
#define D_ 32
#define LOG2E 1.44269504088896340736f

typedef __attribute__((ext_vector_type(8))) short short8;   // 8 x bf16 (4 VGPRs)
typedef __attribute__((ext_vector_type(4))) short short4v;  // 4 x bf16 (8 B)
typedef __attribute__((ext_vector_type(4))) float float4v;  // MFMA C/D frag

// cheap round-to-nearest-even fp32->bf16 (finite inputs only): 3 VALU ops
__device__ inline short f2bf_rne(float f) {
  unsigned u = __builtin_bit_cast(unsigned, f);
  u += 0x7FFFu + ((u >> 16) & 1u);
  return (short)(u >> 16);
}

__device__ inline float fast_exp2(float x) { return __builtin_amdgcn_exp2f(x); }

// ---------------------------------------------------------------------------
// Kernel 1: build fragment-linearized bf16 weights WtF.
// Frag f = nb*8+ks (nb 0..19, ks 0..7). Element (f, lane l, j) = W[k][n],
//   n = nb*16 + (l&15), k = ks*32 + (l>>4)*8 + j.
// log2(e) folded into the Wq columns (n<32).
// ---------------------------------------------------------------------------
__global__ __launch_bounds__(256) void cast_w_kernel(
    const float* __restrict__ Wq, const float* __restrict__ Wk,
    const float* __restrict__ Wv, short* __restrict__ WtF) {
  int i  = blockIdx.x * 256 + threadIdx.x;  // 0..81919
  int j  = i & 7;
  int l  = (i >> 3) & 63;
  int ks = (i >> 9) & 7;
  int nb = i >> 12;
  int n  = nb * 16 + (l & 15);
  int k  = ks * 32 + ((l >> 4) << 3) + j;
  float v;
  if (n < 32)      v = Wq[k * 32 + n] * LOG2E;
  else if (n < 64) v = Wk[k * 32 + (n - 32)];
  else             v = Wv[k * 256 + (n - 64)];
  WtF[i] = f2bf_rne(v);
}

// ---------------------------------------------------------------------------
// Kernel 2: fused QKV projection. 512 blocks x 256 thr (2 blocks/CU),
// 32 pixel rows per block. x staged to LDS once; W B-frags are single
// coalesced 16B loads from fragment-linear WtF (L2-resident).
// V output transposed through LDS -> full-line vT stores.
// ---------------------------------------------------------------------------
__global__ __launch_bounds__(256, 2) void proj_kernel(
    const float* __restrict__ x, const short* __restrict__ WtF,
    const float* __restrict__ bq, const float* __restrict__ bk,
    const float* __restrict__ bv,
    short* __restrict__ qb, short* __restrict__ kb2, short* __restrict__ vT) {
  int blk = blockIdx.x;
  int b  = blk >> 7;
  int r0 = (blk & 127) * 32;
  int t  = threadIdx.x;
  int w  = t >> 6;
  int l  = t & 63;
  int lc = l & 15;
  int q4 = l >> 4;

  __shared__ __align__(16) short sA[32][272];  // 32 rows x 256 k (+16 pad) 17.4 KB
  __shared__ __align__(16) short sV[256][40];  // c x 32 rows (+8 pad)      20.5 KB

  // stage x tile (fp32 -> bf16), once
  {
    int row = t >> 3;
    int c0  = (t & 7) * 32;
    const float* src = x + (size_t)(b * N_ + r0 + row) * C_ + c0;
#pragma unroll
    for (int i = 0; i < 4; i++) {
      float4v v0 = *(const float4v*)(src + i * 8);
      float4v v1 = *(const float4v*)(src + i * 8 + 4);
      short8 s;
      s[0] = f2bf_rne(v0[0]); s[1] = f2bf_rne(v0[1]); s[2] = f2bf_rne(v0[2]); s[3] = f2bf_rne(v0[3]);
      s[4] = f2bf_rne(v1[0]); s[5] = f2bf_rne(v1[1]); s[6] = f2bf_rne(v1[2]); s[7] = f2bf_rne(v1[3]);
      *(short8*)(&sA[row][c0 + i * 8]) = s;
    }
  }
  __syncthreads();

  float4v acc[10];  // [nbo*2 + rt]
#pragma unroll
  for (int i = 0; i < 10; i++) { acc[i][0] = 0.f; acc[i][1] = 0.f; acc[i][2] = 0.f; acc[i][3] = 0.f; }

#pragma unroll
  for (int ks = 0; ks < 8; ks++) {
    short8 af0 = *(const short8*)(&sA[lc][ks * 32 + q4 * 8]);
    short8 af1 = *(const short8*)(&sA[16 + lc][ks * 32 + q4 * 8]);
#pragma unroll
    for (int nbo = 0; nbo < 5; nbo++) {
      int nb = w * 5 + nbo;
      short8 bf = *(const short8*)(WtF + (((nb << 3) + ks) << 9) + l * 8);
      acc[nbo * 2 + 0] = __builtin_amdgcn_mfma_f32_16x16x32_bf16(af0, bf, acc[nbo * 2 + 0], 0, 0, 0);
      acc[nbo * 2 + 1] = __builtin_amdgcn_mfma_f32_16x16x32_bf16(af1, bf, acc[nbo * 2 + 1], 0, 0, 0);
    }
  }

  // epilogue: bias, cast; q/k direct, v -> LDS transpose
#pragma unroll
  for (int nbo = 0; nbo < 5; nbo++) {
    int n = (w * 5 + nbo) * 16 + lc;
    float bias = (n < 32) ? bq[n] * LOG2E : (n < 64) ? bk[n - 32] : bv[n - 64];
#pragma unroll
    for (int rt = 0; rt < 2; rt++) {
#pragma unroll
      for (int r = 0; r < 4; r++) {
        int row = rt * 16 + q4 * 4 + r;  // C-layout: row=(lane>>4)*4+reg
        short s = f2bf_rne(acc[nbo * 2 + rt][r] + bias);
        if (n < 32)      qb [(size_t)(b * N_ + r0 + row) * D_ + n] = s;
        else if (n < 64) kb2[(size_t)(b * N_ + r0 + row) * D_ + (n - 32)] = s;
        else             sV[n - 64][row] = s;
      }
    }
  }
  __syncthreads();

  // vT store: thread t owns channel c=t, writes 32 rows = 64 B (one full line)
  {
    int c = t;
    short8 v0 = *(const short8*)(&sV[c][0]);
    short8 v1 = *(const short8*)(&sV[c][8]);
    short8 v2 = *(const short8*)(&sV[c][16]);
    short8 v3 = *(const short8*)(&sV[c][24]);
    short* dst = vT + (size_t)(b * C_ + c) * N_ + r0;
    *(short8*)(dst)      = v0;
    *(short8*)(dst + 8)  = v1;
    *(short8*)(dst + 16) = v2;
    *(short8*)(dst + 24) = v3;
  }
}

// ---------------------------------------------------------------------------
// Kernel 3: flash attention (fixed-max exp2-domain) + gamma*out + residual.
// 256 blocks x 512 thr (8 waves -> 2/SIMD). Wave specialization:
//   waves 0-3: QK (own 16-row tile) + softmax + sP write, plus PV slice.
//   waves 4-7: PV slice only. Every wave owns 32 output channels.
// kv-loop MANUALLY unrolled x2: two named register sets (A/B) and constant
// sP buffer indices -> everything stays in VGPRs (round 3's dynamic-indexed
// frag arrays were demoted to scratch: MfmaUtil 0.4%, 37x regression).
// ---------------------------------------------------------------------------
__global__ __launch_bounds__(512, 2) void flash_kernel(
    const short* __restrict__ qb, const short* __restrict__ kb,
    const short* __restrict__ vT, const float* __restrict__ xin,
    const float* __restrict__ gptr, float* __restrict__ out) {
  int blk = blockIdx.x;
  int b  = blk & 3;                            // XCD (blk%8) -> single batch
  int qt = (blk >> 3) * 2 + ((blk >> 2) & 1);  // bijective over 0..63 per batch
  int r0 = qt * 64;
  int t  = threadIdx.x;
  int w  = t >> 6;                             // 0..7
  int l  = t & 63;
  int lc = l & 15;
  int q4 = l >> 4;

  __shared__ __align__(16) short sP[2][64][80];  // dbuf P, stride 80 (20.5 KB)
  __shared__ float sL[64];

  const short* kbase = kb + (size_t)b * N_ * D_;
  const short* vbase = vT + (size_t)b * C_ * N_;

  bool qkwave = (w < 4);
  int rq = w & 3;           // QK rowtile for waves 0-3
  int chbase = w * 32;      // PV channel slice, all 8 waves

  // Q as B-frag (B[k=d][n=qrow]); log2e already folded into weights
  short8 qf = *(const short8*)(qb + (size_t)(b * N_ + r0 + rq * 16 + lc) * D_ + q4 * 8);

  const short* kp = kbase + lc * D_ + q4 * 8;
  const short* vp = vbase + (size_t)(chbase + lc) * N_ + q4 * 8;

  // two named register sets -- ALL indices compile-time constant
  short8 kA0, kA1, kA2, kA3, kB0, kB1, kB2, kB3;
  short8 vA0, vA1, vA2, vA3, vB0, vB1, vB2, vB3;  // [cb*2+ks]

  kA0 = *(const short8*)(kp + 0 * 16 * D_);
  kA1 = *(const short8*)(kp + 1 * 16 * D_);
  kA2 = *(const short8*)(kp + 2 * 16 * D_);
  kA3 = *(const short8*)(kp + 3 * 16 * D_);
  vA0 = *(const short8*)(vp + (size_t)0 * 16 * N_ + 0);
  vA1 = *(const short8*)(vp + (size_t)0 * 16 * N_ + 32);
  vA2 = *(const short8*)(vp + (size_t)1 * 16 * N_ + 0);
  vA3 = *(const short8*)(vp + (size_t)1 * 16 * N_ + 32);

  float4v O[8];  // [rt*2 + cb]
#pragma unroll
  for (int i = 0; i < 8; i++) { O[i][0] = 0.f; O[i][1] = 0.f; O[i][2] = 0.f; O[i][3] = 0.f; }
  float l_part = 0.f;

#define QK_PHASE(KR0, KR1, KR2, KR3, BUF)                                      \
  {                                                                            \
    float4v St0, St1, St2, St3;                                                \
    float4v z; z[0] = 0.f; z[1] = 0.f; z[2] = 0.f; z[3] = 0.f;                 \
    St0 = __builtin_amdgcn_mfma_f32_16x16x32_bf16(KR0, qf, z, 0, 0, 0);        \
    St1 = __builtin_amdgcn_mfma_f32_16x16x32_bf16(KR1, qf, z, 0, 0, 0);        \
    St2 = __builtin_amdgcn_mfma_f32_16x16x32_bf16(KR2, qf, z, 0, 0, 0);        \
    St3 = __builtin_amdgcn_mfma_f32_16x16x32_bf16(KR3, qf, z, 0, 0, 0);        \
    float4v* Sts[1];                                                           \
    (void)Sts;                                                                 \
    float ts = 0.f;                                                            \
    {                                                                          \
      float p0 = fast_exp2(St0[0]), p1 = fast_exp2(St0[1]);                    \
      float p2 = fast_exp2(St0[2]), p3 = fast_exp2(St0[3]);                    \
      ts += (p0 + p1) + (p2 + p3);                                             \
      short4v pk; pk[0]=f2bf_rne(p0); pk[1]=f2bf_rne(p1);                      \
      pk[2]=f2bf_rne(p2); pk[3]=f2bf_rne(p3);                                  \
      *(short4v*)(&sP[BUF][rq * 16 + lc][0 * 16 + q4 * 4]) = pk;               \
    }                                                                          \
    {                                                                          \
      float p0 = fast_exp2(St1[0]), p1 = fast_exp2(St1[1]);                    \
      float p2 = fast_exp2(St1[2]), p3 = fast_exp2(St1[3]);                    \
      ts += (p0 + p1) + (p2 + p3);                                             \
      short4v pk; pk[0]=f2bf_rne(p0); pk[1]=f2bf_rne(p1);                      \
      pk[2]=f2bf_rne(p2); pk[3]=f2bf_rne(p3);                                  \
      *(short4v*)(&sP[BUF][rq * 16 + lc][1 * 16 + q4 * 4]) = pk;               \
    }                                                                          \
    {                                                                          \
      float p0 = fast_exp2(St2[0]), p1 = fast_exp2(St2[1]);                    \
      float p2 = fast_exp2(St2[2]), p3 = fast_exp2(St2[3]);                    \
      ts += (p0 + p1) + (p2 + p3);                                             \
      short4v pk; pk[0]=f2bf_rne(p0); pk[1]=f2bf_rne(p1);                      \
      pk[2]=f2bf_rne(p2); pk[3]=f2bf_rne(p3);                                  \
      *(short4v*)(&sP[BUF][rq * 16 + lc][2 * 16 + q4 * 4]) = pk;               \
    }                                                                          \
    {                                                                          \
      float p0 = fast_exp2(St3[0]), p1 = fast_exp2(St3[1]);                    \
      float p2 = fast_exp2(St3[2]), p3 = fast_exp2(St3[3]);                    \
      ts += (p0 + p1) + (p2 + p3);                                             \
      short4v pk; pk[0]=f2bf_rne(p0); pk[1]=f2bf_rne(p1);                      \
      pk[2]=f2bf_rne(p2); pk[3]=f2bf_rne(p3);                                  \
      *(short4v*)(&sP[BUF][rq * 16 + lc][3 * 16 + q4 * 4]) = pk;               \
    }                                                                          \
    l_part += ts;                                                              \
  }

#define PV_PHASE(VR0, VR1, VR2, VR3, BUF)                                      \
  {                                                                            \
    short8 pf[8];                                                              \
    _Pragma("unroll")                                                          \
    for (int rt = 0; rt < 4; rt++) {                                           \
      pf[rt * 2 + 0] = *(const short8*)(&sP[BUF][rt * 16 + lc][q4 * 8]);       \
      pf[rt * 2 + 1] = *(const short8*)(&sP[BUF][rt * 16 + lc][32 + q4 * 8]);  \
    }                                                                          \
    _Pragma("unroll")                                                          \
    for (int rt = 0; rt < 4; rt++) {                                           \
      O[rt * 2 + 0] = __builtin_amdgcn_mfma_f32_16x16x32_bf16(                 \
          pf[rt * 2 + 0], VR0, O[rt * 2 + 0], 0, 0, 0);                        \
      O[rt * 2 + 0] = __builtin_amdgcn_mfma_f32_16x16x32_bf16(                 \
          pf[rt * 2 + 1], VR1, O[rt * 2 + 0], 0, 0, 0);                        \
      O[rt * 2 + 1] = __builtin_amdgcn_mfma_f32_16x16x32_bf16(                 \
          pf[rt * 2 + 0], VR2, O[rt * 2 + 1], 0, 0, 0);                        \
      O[rt * 2 + 1] = __builtin_amdgcn_mfma_f32_16x16x32_bf16(                 \
          pf[rt * 2 + 1], VR3, O[rt * 2 + 1], 0, 0, 0);                        \
    }                                                                          \
  }

  for (int kt = 0; kt < 64; kt += 2) {
    int n1 = kt + 1;
    int n2 = (kt + 2 < 64) ? kt + 2 : 63;  // harmless tail reload

    // ======== phase A: tile kt (regs A, sP[0]); prefetch n1 -> regs B ======
    if (qkwave) {
      kB0 = *(const short8*)(kp + (size_t)n1 * 64 * D_ + 0 * 16 * D_);
      kB1 = *(const short8*)(kp + (size_t)n1 * 64 * D_ + 1 * 16 * D_);
      kB2 = *(const short8*)(kp + (size_t)n1 * 64 * D_ + 2 * 16 * D_);
      kB3 = *(const short8*)(kp + (size_t)n1 * 64 * D_ + 3 * 16 * D_);
    }
    vB0 = *(const short8*)(vp + (size_t)0 * 16 * N_ + (size_t)n1 * 64 + 0);
    vB1 = *(const short8*)(vp + (size_t)0 * 16 * N_ + (size_t)n1 * 64 + 32);
    vB2 = *(const short8*)(vp + (size_t)1 * 16 * N_ + (size_t)n1 * 64 + 0);
    vB3 = *(const short8*)(vp + (size_t)1 * 16 * N_ + (size_t)n1 * 64 + 32);

    if (qkwave) QK_PHASE(kA0, kA1, kA2, kA3, 0);
    __syncthreads();
    PV_PHASE(vA0, vA1, vA2, vA3, 0);

    // ======== phase B: tile n1 (regs B, sP[1]); prefetch n2 -> regs A ======
    if (qkwave) {
      kA0 = *(const short8*)(kp + (size_t)n2 * 64 * D_ + 0 * 16 * D_);
      kA1 = *(const short8*)(kp + (size_t)n2 * 64 * D_ + 1 * 16 * D_);
      kA2 = *(const short8*)(kp + (size_t)n2 * 64 * D_ + 2 * 16 * D_);
      kA3 = *(const short8*)(kp + (size_t)n2 * 64 * D_ + 3 * 16 * D_);
    }
    vA0 = *(const short8*)(vp + (size_t)0 * 16 * N_ + (size_t)n2 * 64 + 0);
    vA1 = *(const short8*)(vp + (size_t)0 * 16 * N_ + (size_t)n2 * 64 + 32);
    vA2 = *(const short8*)(vp + (size_t)1 * 16 * N_ + (size_t)n2 * 64 + 0);
    vA3 = *(const short8*)(vp + (size_t)1 * 16 * N_ + (size_t)n2 * 64 + 32);

    if (qkwave) QK_PHASE(kB0, kB1, kB2, kB3, 1);
    __syncthreads();
    PV_PHASE(vB0, vB1, vB2, vB3, 1);
  }

  // denominator: reduce per-lane partials across the 4 q4 groups
  if (qkwave) {
    float l_tot = l_part + __shfl_xor(l_part, 16, 64);
    l_tot += __shfl_xor(l_tot, 32, 64);
    sL[rq * 16 + lc] = l_tot;
  }
  __syncthreads();

  float g = *gptr;
#pragma unroll
  for (int rt = 0; rt < 4; rt++) {
    float4v lv = *(const float4v*)(&sL[rt * 16 + q4 * 4]);
    float4v inv;
#pragma unroll
    for (int r = 0; r < 4; r++) inv[r] = __builtin_amdgcn_rcpf(lv[r]);
#pragma unroll
    for (int cb = 0; cb < 2; cb++) {
#pragma unroll
      for (int r = 0; r < 4; r++) {
        size_t idx = (size_t)(b * N_ + r0 + rt * 16 + q4 * 4 + r) * C_ + chbase + cb * 16 + lc;
        out[idx] = g * (O[rt * 2 + cb][r] * inv[r]) + xin[idx];
      }
    }
  }
#undef QK_PHASE
#undef PV_PHASE
}

// ---------------------------------------------------------------------------
extern "C" void kernel_launch(void* const* d_in, const int* in_sizes, int n_in,
                              void* d_out, int out_size, void* d_ws, size_t ws_size,
                              hipStream_t stream) {
  const float* x     = (const float*)d_in[0];
  const float* Wq    = (const float*)d_in[1];
  const float* bq    = (const float*)d_in[2];
  const float* Wk    = (const float*)d_in[3];
  const float* bk    = (const float*)d_in[4];
  const float* Wv    = (const float*)d_in[5];
  const float* bv    = (const float*)d_in[6];
  const float* gamma = (const float*)d_in[7];
  float* out = (float*)d_out;

  char* ws = (char*)d_ws;
  short* qb  = (short*)ws;                   // B*N*D bf16  = 1 MB
  short* kb  = (short*)(ws + (1u << 20));    // B*N*D bf16  = 1 MB
  short* vT  = (short*)(ws + (2u << 20));    // B*C*N bf16  = 8 MB (channel-major)
  short* WtF = (short*)(ws + (10u << 20));   // 81920 bf16 fragment-linear = 160 KB

  hipLaunchKernelGGL(cast_w_kernel, dim3(320), dim3(256), 0, stream, Wq, Wk, Wv, WtF);
  hipLaunchKernelGGL(proj_kernel,   dim3(512), dim3(256), 0, stream, x, WtF, bq, bk, bv, qb, kb, vT);
  hipLaunchKernelGGL(flash_kernel,  dim3(256), dim3(512), 0, stream, qb, kb, vT, x, gamma, out);
}

// Round 5
// 164.558 us; speedup vs baseline: 22.9505x; 1.0408x over previous
//
#include <hip/hip_runtime.h>
#include <hip/hip_bf16.h>

#define B_ 4
#define N_ 4096
#define C_ 256
#define D_ 32
#define LOG2E 1.44269504088896340736f

typedef __attribute__((ext_vector_type(8))) short short8;   // 8 x bf16 (4 VGPRs)
typedef __attribute__((ext_vector_type(4))) short short4v;  // 4 x bf16 (8 B)
typedef __attribute__((ext_vector_type(4))) float float4v;  // MFMA C/D frag

// cheap round-to-nearest-even fp32->bf16 (finite inputs only): 3 VALU ops
__device__ inline short f2bf_rne(float f) {
  unsigned u = __builtin_bit_cast(unsigned, f);
  u += 0x7FFFu + ((u >> 16) & 1u);
  return (short)(u >> 16);
}

__device__ inline float fast_exp2(float x) { return __builtin_amdgcn_exp2f(x); }

// ---------------------------------------------------------------------------
// Kernel 1: build fragment-linearized bf16 weights WtF (unchanged layout).
// Frag f = nb*8+ks. Element (f, lane l, j) = W[k][n], n = nb*16+(l&15),
// k = ks*32+(l>>4)*8+j. log2(e) folded into Wq columns.
// ---------------------------------------------------------------------------
__global__ __launch_bounds__(256) void cast_w_kernel(
    const float* __restrict__ Wq, const float* __restrict__ Wk,
    const float* __restrict__ Wv, short* __restrict__ WtF) {
  int i  = blockIdx.x * 256 + threadIdx.x;  // 0..81919
  int j  = i & 7;
  int l  = (i >> 3) & 63;
  int ks = (i >> 9) & 7;
  int nb = i >> 12;
  int n  = nb * 16 + (l & 15);
  int k  = ks * 32 + ((l >> 4) << 3) + j;
  float v;
  if (n < 32)      v = Wq[k * 32 + n] * LOG2E;
  else if (n < 64) v = Wk[k * 32 + (n - 32)];
  else             v = Wv[k * 256 + (n - 64)];
  WtF[i] = f2bf_rne(v);
}

// ---------------------------------------------------------------------------
// Kernel 2: fused QKV projection. 512 blocks x 256 thr, 32 rows/block.
// Outputs: qb row-major [N][32]; kF / vF in MFMA-FRAGMENT-LINEAR order so
// flash loads are lane-contiguous 1KB streams:
//   kF: per kv-tile (64 rows) 4 frags of 512B; frag i covers kv i*16..+15,
//       lane l = (d/8)*16 + (kv&15), 8 shorts of d.
//   vF: per kv-tile 32 frags (f = ks*16 + cb); frag covers kv half ks,
//       channels cb*16..+15; lane l = ((kv&31)/8)*16 + (ch&15), 8 kv shorts.
// ---------------------------------------------------------------------------
__global__ __launch_bounds__(256, 2) void proj_kernel(
    const float* __restrict__ x, const short* __restrict__ WtF,
    const float* __restrict__ bq, const float* __restrict__ bk,
    const float* __restrict__ bv,
    short* __restrict__ qb, short* __restrict__ kF, short* __restrict__ vF) {
  int blk = blockIdx.x;
  int b  = blk >> 7;
  int r0 = (blk & 127) * 32;
  int t  = threadIdx.x;
  int w  = t >> 6;
  int l  = t & 63;
  int lc = l & 15;
  int q4 = l >> 4;

  __shared__ __align__(16) short sA[32][272];  // 32 rows x 256 k (+16 pad) 17.4 KB
  __shared__ __align__(16) short sV[256][40];  // ch x 32 rows (+8 pad)     20.5 KB
  __shared__ __align__(16) short sK[32][36];   // kv x 32 d (+4 pad)         2.3 KB

  // stage x tile (fp32 -> bf16), fully coalesced: thread-linear float4s
  {
    const float* xb = x + (size_t)(b * N_ + r0) * C_;
#pragma unroll
    for (int ch = 0; ch < 8; ch++) {
      int f   = ch * 256 + t;        // float4 index in the 32x256 tile
      int row = f >> 6;
      int col = (f & 63) * 4;
      float4v v = *(const float4v*)(xb + f * 4);
      short4v s;
      s[0] = f2bf_rne(v[0]); s[1] = f2bf_rne(v[1]);
      s[2] = f2bf_rne(v[2]); s[3] = f2bf_rne(v[3]);
      *(short4v*)(&sA[row][col]) = s;
    }
  }
  __syncthreads();

  float4v acc[10];  // [nbo*2 + rt]
#pragma unroll
  for (int i = 0; i < 10; i++) { acc[i][0] = 0.f; acc[i][1] = 0.f; acc[i][2] = 0.f; acc[i][3] = 0.f; }

#pragma unroll
  for (int ks = 0; ks < 8; ks++) {
    short8 af0 = *(const short8*)(&sA[lc][ks * 32 + q4 * 8]);
    short8 af1 = *(const short8*)(&sA[16 + lc][ks * 32 + q4 * 8]);
#pragma unroll
    for (int nbo = 0; nbo < 5; nbo++) {
      int nb = w * 5 + nbo;
      short8 bf = *(const short8*)(WtF + (((nb << 3) + ks) << 9) + l * 8);
      acc[nbo * 2 + 0] = __builtin_amdgcn_mfma_f32_16x16x32_bf16(af0, bf, acc[nbo * 2 + 0], 0, 0, 0);
      acc[nbo * 2 + 1] = __builtin_amdgcn_mfma_f32_16x16x32_bf16(af1, bf, acc[nbo * 2 + 1], 0, 0, 0);
    }
  }

  // epilogue: bias + cast; q direct to global, k -> sK, v -> sV (transpose)
#pragma unroll
  for (int nbo = 0; nbo < 5; nbo++) {
    int n = (w * 5 + nbo) * 16 + lc;
    float bias = (n < 32) ? bq[n] * LOG2E : (n < 64) ? bk[n - 32] : bv[n - 64];
#pragma unroll
    for (int rt = 0; rt < 2; rt++) {
#pragma unroll
      for (int r = 0; r < 4; r++) {
        int row = rt * 16 + q4 * 4 + r;  // C-layout: row=(lane>>4)*4+reg
        short s = f2bf_rne(acc[nbo * 2 + rt][r] + bias);
        if (n < 32)      qb[(size_t)(b * N_ + r0 + row) * D_ + n] = s;
        else if (n < 64) sK[row][n - 32] = s;
        else             sV[n - 64][row] = s;
      }
    }
  }
  __syncthreads();

  int kt  = r0 >> 6;          // kv-tile this block's 32 rows belong to
  int ks0 = (r0 >> 5) & 1;    // which 32-kv half of the tile

  // vF writer: thread t = channel c, writes 4 x 16B pieces of frag ks0*16+(c/16)
  {
    int c = t;
    size_t tb = ((size_t)(b * 64 + kt) * 32 + ks0 * 16 + (c >> 4)) * 512;
#pragma unroll
    for (int rg = 0; rg < 4; rg++) {
      short8 vv = *(const short8*)(&sV[c][rg * 8]);
      *(short8*)(vF + tb + (rg * 16 + (c & 15)) * 8) = vv;
    }
  }
  // kF writer: threads 0..127; (row, d-group) -> frag ks0*2+(row/16)
  if (t < 128) {
    int row = t >> 2, dg = t & 3;
    size_t tb = ((size_t)(b * 64 + kt) * 4 + ks0 * 2 + (row >> 4)) * 512;
    short8 kv = *(const short8*)(&sK[row][dg * 8]);
    *(short8*)(kF + tb + (dg * 16 + (row & 15)) * 8) = kv;
  }
}

// ---------------------------------------------------------------------------
// Kernel 3: flash attention (fixed-max exp2-domain) + gamma*out + residual.
// 256 blocks x 512 thr. NO barriers in the kv loop: each wave owns 16 Q-rows
// x one kv-half (h = w>>2) and round-trips P through its OWN sP region
// (same-wave LDS dep -> lgkmcnt only). K and V double-buffered in registers
// (constant-indexed; round 3 taught us dynamic indexing = scratch death).
// kv-halves merged once at the end via LDS (fixed-max => pure add).
// ---------------------------------------------------------------------------
__global__ __launch_bounds__(512, 2) void flash_kernel(
    const short* __restrict__ qb, const short* __restrict__ kF,
    const short* __restrict__ vF, const float* __restrict__ xin,
    const float* __restrict__ gptr, float* __restrict__ out) {
  int blk = blockIdx.x;
  int b  = blk & 3;                            // XCD (blk%8) -> single batch
  int qt = (blk >> 3) * 2 + ((blk >> 2) & 1);  // bijective over 0..63 per batch
  int r0 = qt * 64;
  int t  = threadIdx.x;
  int w  = t >> 6;                             // 0..7
  int l  = t & 63;
  int lc = l & 15;
  int q4 = l >> 4;
  int rq = w & 3;                              // Q rowtile (16 rows)
  int h  = w >> 2;                             // kv half (0: kv 0..31, 1: 32..63)

  __shared__ __align__(16) short sP[8][16][36];      // per-wave P, 9.2 KB
  __shared__ __align__(16) float4v mbuf[2][16][64];  // merge buffer, 32 KB
  __shared__ float sLh[64];
  __shared__ float sLm[64];

  // Q as B-frag: B[k=d][n=qrow-in-16], qrow = rq*16+lc (log2e pre-folded)
  short8 qf = *(const short8*)(qb + (size_t)(b * N_ + r0 + rq * 16 + lc) * D_ + q4 * 8);

  const short* kp = kF + (size_t)b * (64 * 4 * 512) + h * (2 * 512) + l * 8;
  const short* vp = vF + (size_t)b * (64 * 32 * 512) + h * (16 * 512) + l * 8;

  short8 vA[16], vB[16];          // V frags, double-buffered (const-indexed)
  short8 kX0, kX1, kY0, kY1;      // K frags, double-buffered

  kX0 = *(const short8*)(kp);
  kX1 = *(const short8*)(kp + 512);
#pragma unroll
  for (int cb = 0; cb < 16; cb++)
    vA[cb] = *(const short8*)(vp + cb * 512);

  float4v O[16];
#pragma unroll
  for (int i = 0; i < 16; i++) { O[i][0] = 0.f; O[i][1] = 0.f; O[i][2] = 0.f; O[i][3] = 0.f; }
  float l_part = 0.f;

  short (*sPw)[36] = sP[w];

#define TILE_PHASE(KC0, KC1, KP0, KP1, VCUR, VNXT, TI)                          \
  {                                                                             \
    int nt = ((TI) + 1 < 64) ? (TI) + 1 : 63;                                   \
    _Pragma("unroll")                                                           \
    for (int cb = 0; cb < 16; cb++)                                             \
      VNXT[cb] = *(const short8*)(vp + (size_t)nt * (32 * 512) + cb * 512);     \
    KP0 = *(const short8*)(kp + (size_t)nt * (4 * 512));                        \
    KP1 = *(const short8*)(kp + (size_t)nt * (4 * 512) + 512);                  \
    float4v z; z[0] = 0.f; z[1] = 0.f; z[2] = 0.f; z[3] = 0.f;                  \
    float4v St0 = __builtin_amdgcn_mfma_f32_16x16x32_bf16(KC0, qf, z, 0, 0, 0); \
    float4v St1 = __builtin_amdgcn_mfma_f32_16x16x32_bf16(KC1, qf, z, 0, 0, 0); \
    float p0 = fast_exp2(St0[0]), p1 = fast_exp2(St0[1]);                       \
    float p2 = fast_exp2(St0[2]), p3 = fast_exp2(St0[3]);                       \
    float p4 = fast_exp2(St1[0]), p5 = fast_exp2(St1[1]);                       \
    float p6 = fast_exp2(St1[2]), p7 = fast_exp2(St1[3]);                       \
    l_part += ((p0 + p1) + (p2 + p3)) + ((p4 + p5) + (p6 + p7));                \
    short4v pk0, pk1;                                                           \
    pk0[0] = f2bf_rne(p0); pk0[1] = f2bf_rne(p1);                               \
    pk0[2] = f2bf_rne(p2); pk0[3] = f2bf_rne(p3);                               \
    pk1[0] = f2bf_rne(p4); pk1[1] = f2bf_rne(p5);                               \
    pk1[2] = f2bf_rne(p6); pk1[3] = f2bf_rne(p7);                               \
    *(short4v*)(&sPw[lc][q4 * 4]) = pk0;                                        \
    *(short4v*)(&sPw[lc][16 + q4 * 4]) = pk1;                                   \
    short8 pf = *(const short8*)(&sPw[lc][q4 * 8]);                             \
    _Pragma("unroll")                                                           \
    for (int cb = 0; cb < 16; cb++)                                             \
      O[cb] = __builtin_amdgcn_mfma_f32_16x16x32_bf16(pf, VCUR[cb], O[cb], 0, 0, 0); \
  }

  for (int kt = 0; kt < 64; kt += 2) {
    TILE_PHASE(kX0, kX1, kY0, kY1, vA, vB, kt);
    TILE_PHASE(kY0, kY1, kX0, kX1, vB, vA, kt + 1);
  }
#undef TILE_PHASE

  // ---- kv-half merge (fixed-max: pure add) ----
  float l_tot = l_part + __shfl_xor(l_part, 16, 64);
  l_tot += __shfl_xor(l_tot, 32, 64);   // lane (lc,*) holds l for qrow rq*16+lc
  bool lo = (h == 0);
  if (!lo && q4 == 0) sLh[rq * 16 + lc] = l_tot;
  __syncthreads();
  if (lo && q4 == 0) sLm[rq * 16 + lc] = l_tot + sLh[rq * 16 + lc];

  if (w == 4 || w == 5) {
#pragma unroll
    for (int cb = 0; cb < 16; cb++) mbuf[w - 4][cb][l] = O[cb];
  }
  __syncthreads();
  if (w == 0 || w == 1) {
#pragma unroll
    for (int cb = 0; cb < 16; cb++) {
      float4v m = mbuf[w][cb][l];
      O[cb][0] += m[0]; O[cb][1] += m[1]; O[cb][2] += m[2]; O[cb][3] += m[3];
    }
  }
  __syncthreads();
  if (w == 6 || w == 7) {
#pragma unroll
    for (int cb = 0; cb < 16; cb++) mbuf[w - 6][cb][l] = O[cb];
  }
  __syncthreads();
  if (w == 2 || w == 3) {
#pragma unroll
    for (int cb = 0; cb < 16; cb++) {
      float4v m = mbuf[w - 2][cb][l];
      O[cb][0] += m[0]; O[cb][1] += m[1]; O[cb][2] += m[2]; O[cb][3] += m[3];
    }
  }

  // ---- epilogue (lo waves): normalize, gamma*attn + residual ----
  if (lo) {
    float g = *gptr;
    float4v lv = *(const float4v*)(&sLm[rq * 16 + q4 * 4]);
    float4v inv;
#pragma unroll
    for (int r = 0; r < 4; r++) inv[r] = __builtin_amdgcn_rcpf(lv[r]);
#pragma unroll
    for (int cb = 0; cb < 16; cb++) {
#pragma unroll
      for (int r = 0; r < 4; r++) {
        size_t idx = (size_t)(b * N_ + r0 + rq * 16 + q4 * 4 + r) * C_ + cb * 16 + lc;
        out[idx] = g * (O[cb][r] * inv[r]) + xin[idx];
      }
    }
  }
}

// ---------------------------------------------------------------------------
extern "C" void kernel_launch(void* const* d_in, const int* in_sizes, int n_in,
                              void* d_out, int out_size, void* d_ws, size_t ws_size,
                              hipStream_t stream) {
  const float* x     = (const float*)d_in[0];
  const float* Wq    = (const float*)d_in[1];
  const float* bq    = (const float*)d_in[2];
  const float* Wk    = (const float*)d_in[3];
  const float* bk    = (const float*)d_in[4];
  const float* Wv    = (const float*)d_in[5];
  const float* bv    = (const float*)d_in[6];
  const float* gamma = (const float*)d_in[7];
  float* out = (float*)d_out;

  char* ws = (char*)d_ws;
  short* qb  = (short*)ws;                   // B*N*D bf16  = 1 MB (row-major)
  short* kF  = (short*)(ws + (1u << 20));    // B*N*D bf16  = 1 MB (fragment-linear)
  short* vF  = (short*)(ws + (2u << 20));    // B*N*C bf16  = 8 MB (fragment-linear)
  short* WtF = (short*)(ws + (10u << 20));   // 81920 bf16 fragment-linear = 160 KB

  hipLaunchKernelGGL(cast_w_kernel, dim3(320), dim3(256), 0, stream, Wq, Wk, Wv, WtF);
  hipLaunchKernelGGL(proj_kernel,   dim3(512), dim3(256), 0, stream, x, WtF, bq, bk, bv, qb, kF, vF);
  hipLaunchKernelGGL(flash_kernel,  dim3(256), dim3(512), 0, stream, qb, kF, vF, x, gamma, out);
}

// Round 6
// 157.305 us; speedup vs baseline: 24.0086x; 1.0461x over previous
//
#include <hip/hip_runtime.h>
#include <hip/hip_bf16.h>

#define B_ 4
#define N_ 4096
#define C_ 256
#define D_ 32
#define LOG2E 1.44269504088896340736f

typedef __attribute__((ext_vector_type(8))) short short8;   // 8 x bf16 (4 VGPRs)
typedef __attribute__((ext_vector_type(4))) short short4v;  // 4 x bf16 (8 B)
typedef __attribute__((ext_vector_type(4))) float float4v;  // MFMA C/D frag

// cheap round-to-nearest-even fp32->bf16 (finite inputs only): 3 VALU ops
__device__ inline short f2bf_rne(float f) {
  unsigned u = __builtin_bit_cast(unsigned, f);
  u += 0x7FFFu + ((u >> 16) & 1u);
  return (short)(u >> 16);
}
__device__ inline float bf2f(short s) {
  unsigned u = ((unsigned)(unsigned short)s) << 16;
  return __builtin_bit_cast(float, u);
}
__device__ inline float fast_exp2(float x) { return __builtin_amdgcn_exp2f(x); }

// ---------------------------------------------------------------------------
// Kernel 1: fragment-linearized bf16 weights WtF. Frag f = nb*8+ks.
// Element (f, lane l, j) = W[k][n], n = nb*16+(l&15), k = ks*32+(l>>4)*8+j.
// log2(e) folded into Wq columns.
// ---------------------------------------------------------------------------
__global__ __launch_bounds__(256) void cast_w_kernel(
    const float* __restrict__ Wq, const float* __restrict__ Wk,
    const float* __restrict__ Wv, short* __restrict__ WtF) {
  int i  = blockIdx.x * 256 + threadIdx.x;  // 0..81919
  int j  = i & 7;
  int l  = (i >> 3) & 63;
  int ks = (i >> 9) & 7;
  int nb = i >> 12;
  int n  = nb * 16 + (l & 15);
  int k  = ks * 32 + ((l >> 4) << 3) + j;
  float v;
  if (n < 32)      v = Wq[k * 32 + n] * LOG2E;
  else if (n < 64) v = Wk[k * 32 + (n - 32)];
  else             v = Wv[k * 256 + (n - 64)];
  WtF[i] = f2bf_rne(v);
}

// ---------------------------------------------------------------------------
// Kernel 2: fused QKV projection. 512 blocks x 256 thr, 4 blocks/CU.
// Wave w handles nb = nbo*4 + w  ->  epilogue branches are wave-uniform:
//   nbo==0: w0,w1 -> q rows; w2,w3 -> k rows. nbo>=1: all v.
// Outputs qb row-major; kF/vF MFMA-fragment-linear (see round-5 layout).
// ---------------------------------------------------------------------------
__global__ __launch_bounds__(256, 4) void proj_kernel(
    const float* __restrict__ x, const short* __restrict__ WtF,
    const float* __restrict__ bq, const float* __restrict__ bk,
    const float* __restrict__ bv,
    short* __restrict__ qb, short* __restrict__ kF, short* __restrict__ vF) {
  int blk = blockIdx.x;
  int b  = blk >> 7;
  int r0 = (blk & 127) * 32;
  int t  = threadIdx.x;
  int w  = t >> 6;
  int l  = t & 63;
  int lc = l & 15;
  int q4 = l >> 4;

  __shared__ __align__(16) short sA[32][272];  // 32 rows x 256 k (+16 pad)
  __shared__ __align__(16) short sV[256][40];  // ch x 32 rows (+8 pad)
  __shared__ __align__(16) short sK[32][36];   // kv x 32 d (+4 pad)

  // stage x tile (fp32 -> bf16), thread-linear float4s (fully coalesced)
  {
    const float* xb = x + (size_t)(b * N_ + r0) * C_;
#pragma unroll
    for (int ch = 0; ch < 8; ch++) {
      int f   = ch * 256 + t;
      int row = f >> 6;
      int col = (f & 63) * 4;
      float4v v = *(const float4v*)(xb + f * 4);
      short4v s;
      s[0] = f2bf_rne(v[0]); s[1] = f2bf_rne(v[1]);
      s[2] = f2bf_rne(v[2]); s[3] = f2bf_rne(v[3]);
      *(short4v*)(&sA[row][col]) = s;
    }
  }
  __syncthreads();

  float4v acc[10];  // [nbo*2 + rt]
#pragma unroll
  for (int i = 0; i < 10; i++) { acc[i][0] = 0.f; acc[i][1] = 0.f; acc[i][2] = 0.f; acc[i][3] = 0.f; }

#pragma unroll
  for (int ks = 0; ks < 8; ks++) {
    short8 af0 = *(const short8*)(&sA[lc][ks * 32 + q4 * 8]);
    short8 af1 = *(const short8*)(&sA[16 + lc][ks * 32 + q4 * 8]);
#pragma unroll
    for (int nbo = 0; nbo < 5; nbo++) {
      int nb = nbo * 4 + w;
      short8 bf = *(const short8*)(WtF + (((nb << 3) + ks) << 9) + l * 8);
      acc[nbo * 2 + 0] = __builtin_amdgcn_mfma_f32_16x16x32_bf16(af0, bf, acc[nbo * 2 + 0], 0, 0, 0);
      acc[nbo * 2 + 1] = __builtin_amdgcn_mfma_f32_16x16x32_bf16(af1, bf, acc[nbo * 2 + 1], 0, 0, 0);
    }
  }

  // epilogue: bias + cast; wave-uniform routing
#pragma unroll
  for (int nbo = 0; nbo < 5; nbo++) {
    float bias;
    if (nbo == 0) bias = (w < 2) ? bq[w * 16 + lc] * LOG2E : bk[(w - 2) * 16 + lc];
    else          bias = bv[(nbo - 1) * 64 + w * 16 + lc];
#pragma unroll
    for (int rt = 0; rt < 2; rt++) {
#pragma unroll
      for (int r = 0; r < 4; r++) {
        int row = rt * 16 + q4 * 4 + r;  // C-layout: row=(lane>>4)*4+reg
        short s = f2bf_rne(acc[nbo * 2 + rt][r] + bias);
        if (nbo == 0) {
          if (w < 2) qb[(size_t)(b * N_ + r0 + row) * D_ + w * 16 + lc] = s;
          else       sK[row][(w - 2) * 16 + lc] = s;
        } else {
          sV[(nbo - 1) * 64 + w * 16 + lc][row] = s;
        }
      }
    }
  }
  __syncthreads();

  int kt  = r0 >> 6;          // kv-tile these 32 rows belong to
  int ks0 = (r0 >> 5) & 1;    // which 32-kv half of the tile

  // vF writer: thread t = channel c; frag f = ks0*16 + c/16
  {
    int c = t;
    size_t tb = ((size_t)(b * 64 + kt) * 32 + ks0 * 16 + (c >> 4)) * 512;
#pragma unroll
    for (int rg = 0; rg < 4; rg++) {
      short8 vv = *(const short8*)(&sV[c][rg * 8]);
      *(short8*)(vF + tb + (rg * 16 + (c & 15)) * 8) = vv;
    }
  }
  // kF writer: threads 0..127
  if (t < 128) {
    int row = t >> 2, dg = t & 3;
    size_t tb = ((size_t)(b * 64 + kt) * 4 + ks0 * 2 + (row >> 4)) * 512;
    short8 kv = *(const short8*)(&sK[row][dg * 8]);
    *(short8*)(kF + tb + (dg * 16 + (row & 15)) * 8) = kv;
  }
}

// ---------------------------------------------------------------------------
// Kernel 3a: flash partial. 512 blocks x 512 thr (2 blocks/CU, 4 waves/SIMD).
// Block = (batch b, Q-tile qt of 64 rows, kv-half hb of 2048). 8 waves:
//   QK: waves 0-3 compute St = K*Q^T for rowtile rq=w over full 64-kv tile.
//   PV: ALL waves; wave (kh=w>>2, cq=w&3) does O[64q][64ch] over its 32-kv
//       half of the tile -> V frags read exactly once per block, P LDS reads
//       4KB/wave. kh partials merged through LDS at the end (fixed-max =>
//       pure add). Partial O (bf16) + l (fp32) to workspace.
// K/V single-buffered registers reloaded right after last use (WAR-safe,
// const-indexed). One barrier per tile (sP LDS double-buffer via pointer).
// ---------------------------------------------------------------------------
__global__ __launch_bounds__(512, 4) void flash_partial_kernel(
    const short* __restrict__ qb, const short* __restrict__ kF,
    const short* __restrict__ vF, short* __restrict__ obuf,
    float* __restrict__ lbuf) {
  int blk = blockIdx.x;
  int b  = blk & 3;            // XCD (blk%8) -> (batch, kv-half): L2 locality
  int hb = (blk >> 2) & 1;
  int qt = blk >> 3;           // 0..63
  int r0 = qt * 64;
  int t  = threadIdx.x;
  int w  = t >> 6;
  int l  = t & 63;
  int lc = l & 15;
  int q4 = l >> 4;
  int rq = w & 3;              // QK rowtile for waves 0-3
  int kh = w >> 2;             // kv-half-of-tile for PV
  int cq = w & 3;              // 64-channel quarter for PV

  __shared__ __align__(16) short sP[2][64][72];  // 18.4 KB, [q][kv]

  int p = (b * 64 + qt) * 2 + hb;  // partial index

  // Q as B-frag (n=q, k=d); log2e pre-folded
  short8 qf = *(const short8*)(qb + (size_t)(b * N_ + r0 + rq * 16 + lc) * D_ + q4 * 8);

  const short* kpb = kF + ((size_t)(b * 64 + hb * 32) * 4) * 512 + l * 8;
  const short* vpb = vF + ((size_t)(b * 64 + hb * 32) * 32 + kh * 16 + cq * 4) * 512 + l * 8;

  short8 kr0, kr1, kr2, kr3;   // K A-frags (kv blocks 0..3 of current tile)
  short8 vr0, vr1, vr2, vr3;   // V B-frags (this wave's 4 cb, its kv-half)
  kr0 = *(const short8*)(kpb + 0 * 512);
  kr1 = *(const short8*)(kpb + 1 * 512);
  kr2 = *(const short8*)(kpb + 2 * 512);
  kr3 = *(const short8*)(kpb + 3 * 512);
  vr0 = *(const short8*)(vpb + 0 * 512);
  vr1 = *(const short8*)(vpb + 1 * 512);
  vr2 = *(const short8*)(vpb + 2 * 512);
  vr3 = *(const short8*)(vpb + 3 * 512);

  float4v O[16];  // [rt*4 + cb]: 64 q-rows x 64 ch
#pragma unroll
  for (int i = 0; i < 16; i++) { O[i][0] = 0.f; O[i][1] = 0.f; O[i][2] = 0.f; O[i][3] = 0.f; }
  float l_part = 0.f;

  for (int ti = 0; ti < 32; ti++) {
    short* sPb = &sP[ti & 1][0][0];
    size_t nto = (size_t)((ti + 1 < 32) ? ti + 1 : 31);  // branchless tail

    if (w < 4) {
      float4v z; z[0] = 0.f; z[1] = 0.f; z[2] = 0.f; z[3] = 0.f;
      float4v St0 = __builtin_amdgcn_mfma_f32_16x16x32_bf16(kr0, qf, z, 0, 0, 0);
      float4v St1 = __builtin_amdgcn_mfma_f32_16x16x32_bf16(kr1, qf, z, 0, 0, 0);
      float4v St2 = __builtin_amdgcn_mfma_f32_16x16x32_bf16(kr2, qf, z, 0, 0, 0);
      float4v St3 = __builtin_amdgcn_mfma_f32_16x16x32_bf16(kr3, qf, z, 0, 0, 0);
      // reload K for next tile (WAR after MFMAs; ~400 cyc to next use)
      kr0 = *(const short8*)(kpb + nto * 2048 + 0 * 512);
      kr1 = *(const short8*)(kpb + nto * 2048 + 1 * 512);
      kr2 = *(const short8*)(kpb + nto * 2048 + 2 * 512);
      kr3 = *(const short8*)(kpb + nto * 2048 + 3 * 512);
      // fixed-max softmax numerators; per-lane denominator partial (q = lc)
      short* rowp = sPb + (rq * 16 + lc) * 72 + q4 * 4;
      float ts;
      {
        float p0 = fast_exp2(St0[0]), p1 = fast_exp2(St0[1]);
        float p2 = fast_exp2(St0[2]), p3 = fast_exp2(St0[3]);
        ts = (p0 + p1) + (p2 + p3);
        short4v pk; pk[0] = f2bf_rne(p0); pk[1] = f2bf_rne(p1);
        pk[2] = f2bf_rne(p2); pk[3] = f2bf_rne(p3);
        *(short4v*)(rowp + 0) = pk;
      }
      {
        float p0 = fast_exp2(St1[0]), p1 = fast_exp2(St1[1]);
        float p2 = fast_exp2(St1[2]), p3 = fast_exp2(St1[3]);
        ts += (p0 + p1) + (p2 + p3);
        short4v pk; pk[0] = f2bf_rne(p0); pk[1] = f2bf_rne(p1);
        pk[2] = f2bf_rne(p2); pk[3] = f2bf_rne(p3);
        *(short4v*)(rowp + 16) = pk;
      }
      {
        float p0 = fast_exp2(St2[0]), p1 = fast_exp2(St2[1]);
        float p2 = fast_exp2(St2[2]), p3 = fast_exp2(St2[3]);
        ts += (p0 + p1) + (p2 + p3);
        short4v pk; pk[0] = f2bf_rne(p0); pk[1] = f2bf_rne(p1);
        pk[2] = f2bf_rne(p2); pk[3] = f2bf_rne(p3);
        *(short4v*)(rowp + 32) = pk;
      }
      {
        float p0 = fast_exp2(St3[0]), p1 = fast_exp2(St3[1]);
        float p2 = fast_exp2(St3[2]), p3 = fast_exp2(St3[3]);
        ts += (p0 + p1) + (p2 + p3);
        short4v pk; pk[0] = f2bf_rne(p0); pk[1] = f2bf_rne(p1);
        pk[2] = f2bf_rne(p2); pk[3] = f2bf_rne(p3);
        *(short4v*)(rowp + 48) = pk;
      }
      l_part += ts;
    }

    __syncthreads();

    // PV: this wave's kv-half (K=32 single step) x 64 channels
#pragma unroll
    for (int rt = 0; rt < 4; rt++) {
      short8 pf = *(const short8*)(sPb + (rt * 16 + lc) * 72 + kh * 32 + q4 * 8);
      O[rt * 4 + 0] = __builtin_amdgcn_mfma_f32_16x16x32_bf16(pf, vr0, O[rt * 4 + 0], 0, 0, 0);
      O[rt * 4 + 1] = __builtin_amdgcn_mfma_f32_16x16x32_bf16(pf, vr1, O[rt * 4 + 1], 0, 0, 0);
      O[rt * 4 + 2] = __builtin_amdgcn_mfma_f32_16x16x32_bf16(pf, vr2, O[rt * 4 + 2], 0, 0, 0);
      O[rt * 4 + 3] = __builtin_amdgcn_mfma_f32_16x16x32_bf16(pf, vr3, O[rt * 4 + 3], 0, 0, 0);
    }
    // reload V for next tile (WAR after PV; ~full phase to next use)
    vr0 = *(const short8*)(vpb + nto * 16384 + 0 * 512);
    vr1 = *(const short8*)(vpb + nto * 16384 + 1 * 512);
    vr2 = *(const short8*)(vpb + nto * 16384 + 2 * 512);
    vr3 = *(const short8*)(vpb + nto * 16384 + 3 * 512);
  }

  // ---- kh-merge inside block via reused sP LDS (fixed-max: pure add) ----
  __syncthreads();
  short* lds16 = &sP[0][0][0];
  if (w == 4 || w == 5) {
    int slot = w - 4;
#pragma unroll
    for (int f = 0; f < 16; f++)
#pragma unroll
      for (int r = 0; r < 4; r++)
        lds16[((slot * 16 + f) * 4 + r) * 64 + l] = f2bf_rne(O[f][r]);
  }
  __syncthreads();
  if (w == 0 || w == 1) {
#pragma unroll
    for (int f = 0; f < 16; f++)
#pragma unroll
      for (int r = 0; r < 4; r++)
        O[f][r] += bf2f(lds16[((w * 16 + f) * 4 + r) * 64 + l]);
  }
  __syncthreads();
  if (w == 6 || w == 7) {
    int slot = w - 6;
#pragma unroll
    for (int f = 0; f < 16; f++)
#pragma unroll
      for (int r = 0; r < 4; r++)
        lds16[((slot * 16 + f) * 4 + r) * 64 + l] = f2bf_rne(O[f][r]);
  }
  __syncthreads();
  if (w == 2 || w == 3) {
#pragma unroll
    for (int f = 0; f < 16; f++)
#pragma unroll
      for (int r = 0; r < 4; r++)
        O[f][r] += bf2f(lds16[(((w - 2) * 16 + f) * 4 + r) * 64 + l]);
  }

  // ---- store partials (waves 0-3 hold the merged tile halves) ----
  if (w < 4) {
    short* ob = obuf + (size_t)p * (64 * 256);
#pragma unroll
    for (int rt = 0; rt < 4; rt++)
#pragma unroll
      for (int cb = 0; cb < 4; cb++)
#pragma unroll
        for (int r = 0; r < 4; r++)
          ob[(rt * 16 + q4 * 4 + r) * 256 + cq * 64 + cb * 16 + lc] =
              f2bf_rne(O[rt * 4 + cb][r]);
    float l_tot = l_part + __shfl_xor(l_part, 16, 64);
    l_tot += __shfl_xor(l_tot, 32, 64);
    if (l < 16) lbuf[(size_t)p * 64 + rq * 16 + l] = l_tot;
  }
}

// ---------------------------------------------------------------------------
// Kernel 3b: merge the two kv-half partials, normalize, gamma*attn + x.
// 256 blocks x 256 thr; ~50 MB traffic.
// ---------------------------------------------------------------------------
__global__ __launch_bounds__(256) void merge_kernel(
    const short* __restrict__ obuf, const float* __restrict__ lbuf,
    const float* __restrict__ xin, const float* __restrict__ gptr,
    float* __restrict__ out) {
  int blk = blockIdx.x;   // = b*64 + qt
  int t   = threadIdx.x;
  float g = *gptr;
  const short* o0 = obuf + (size_t)(blk * 2 + 0) * 16384;
  const short* o1 = obuf + (size_t)(blk * 2 + 1) * 16384;
  const float* l0 = lbuf + (size_t)(blk * 2 + 0) * 64;
  const float* l1 = lbuf + (size_t)(blk * 2 + 1) * 64;
  size_t gbase = (size_t)blk * 16384;
#pragma unroll
  for (int i = 0; i < 8; i++) {
    int j   = i * 256 + t;        // short8 group; row = j>>5 (uniform per i)
    int row = j >> 5;
    short8 a = *(const short8*)(o0 + j * 8);
    short8 c = *(const short8*)(o1 + j * 8);
    float linv = __builtin_amdgcn_rcpf(l0[row] + l1[row]);
    size_t gi = gbase + (size_t)j * 8;
    float4v x0 = *(const float4v*)(xin + gi);
    float4v x1 = *(const float4v*)(xin + gi + 4);
    float4v r0v, r1v;
#pragma unroll
    for (int e = 0; e < 4; e++)
      r0v[e] = g * ((bf2f(a[e]) + bf2f(c[e])) * linv) + x0[e];
#pragma unroll
    for (int e = 0; e < 4; e++)
      r1v[e] = g * ((bf2f(a[e + 4]) + bf2f(c[e + 4])) * linv) + x1[e];
    *(float4v*)(out + gi)     = r0v;
    *(float4v*)(out + gi + 4) = r1v;
  }
}

// ---------------------------------------------------------------------------
extern "C" void kernel_launch(void* const* d_in, const int* in_sizes, int n_in,
                              void* d_out, int out_size, void* d_ws, size_t ws_size,
                              hipStream_t stream) {
  const float* x     = (const float*)d_in[0];
  const float* Wq    = (const float*)d_in[1];
  const float* bq    = (const float*)d_in[2];
  const float* Wk    = (const float*)d_in[3];
  const float* bk    = (const float*)d_in[4];
  const float* Wv    = (const float*)d_in[5];
  const float* bv    = (const float*)d_in[6];
  const float* gamma = (const float*)d_in[7];
  float* out = (float*)d_out;

  char* ws = (char*)d_ws;
  short* qb   = (short*)ws;                   // 1 MB   row-major [N][32]
  short* kF   = (short*)(ws + (1u << 20));    // 1 MB   fragment-linear
  short* vF   = (short*)(ws + (2u << 20));    // 8 MB   fragment-linear
  short* WtF  = (short*)(ws + (10u << 20));   // 160 KB fragment-linear
  short* obuf = (short*)(ws + (11u << 20));   // 16 MB  bf16 partial O [512][64][256]
  float* lbuf = (float*)(ws + (28u << 20));   // 128 KB fp32 partial l [512][64]

  hipLaunchKernelGGL(cast_w_kernel,      dim3(320), dim3(256), 0, stream, Wq, Wk, Wv, WtF);
  hipLaunchKernelGGL(proj_kernel,        dim3(512), dim3(256), 0, stream, x, WtF, bq, bk, bv, qb, kF, vF);
  hipLaunchKernelGGL(flash_partial_kernel, dim3(512), dim3(512), 0, stream, qb, kF, vF, obuf, lbuf);
  hipLaunchKernelGGL(merge_kernel,       dim3(256), dim3(256), 0, stream, obuf, lbuf, x, gamma, out);
}

// Round 7
// 147.745 us; speedup vs baseline: 25.5622x; 1.0647x over previous
//
#include <hip/hip_runtime.h>
#include <hip/hip_bf16.h>

#define B_ 4
#define N_ 4096
#define C_ 256
#define D_ 32
#define LOG2E 1.44269504088896340736f
#define MFMA16 __builtin_amdgcn_mfma_f32_16x16x32_bf16

typedef __attribute__((ext_vector_type(8))) short short8;   // 8 x bf16 (4 VGPRs)
typedef __attribute__((ext_vector_type(4))) short short4v;  // 4 x bf16 (8 B)
typedef __attribute__((ext_vector_type(4))) float float4v;  // MFMA C/D frag

// cheap round-to-nearest-even fp32->bf16 (finite inputs only): 3 VALU ops
__device__ inline short f2bf_rne(float f) {
  unsigned u = __builtin_bit_cast(unsigned, f);
  u += 0x7FFFu + ((u >> 16) & 1u);
  return (short)(u >> 16);
}
__device__ inline float bf2f(short s) {
  unsigned u = ((unsigned)(unsigned short)s) << 16;
  return __builtin_bit_cast(float, u);
}
__device__ inline float fast_exp2(float x) { return __builtin_amdgcn_exp2f(x); }

// ---------------------------------------------------------------------------
// Kernel 1: fragment-linearized bf16 weights WtF. Frag f = nb*8+ks.
// Element (f, lane l, j) = W[k][n], n = nb*16+(l&15), k = ks*32+(l>>4)*8+j.
// log2(e) folded into Wq columns.
// ---------------------------------------------------------------------------
__global__ __launch_bounds__(256) void cast_w_kernel(
    const float* __restrict__ Wq, const float* __restrict__ Wk,
    const float* __restrict__ Wv, short* __restrict__ WtF) {
  int i  = blockIdx.x * 256 + threadIdx.x;  // 0..81919
  int j  = i & 7;
  int l  = (i >> 3) & 63;
  int ks = (i >> 9) & 7;
  int nb = i >> 12;
  int n  = nb * 16 + (l & 15);
  int k  = ks * 32 + ((l >> 4) << 3) + j;
  float v;
  if (n < 32)      v = Wq[k * 32 + n] * LOG2E;
  else if (n < 64) v = Wk[k * 32 + (n - 32)];
  else             v = Wv[k * 256 + (n - 64)];
  WtF[i] = f2bf_rne(v);
}

// ---------------------------------------------------------------------------
// Kernel 2: fused QKV projection (unchanged from round 6).
// ---------------------------------------------------------------------------
__global__ __launch_bounds__(256, 4) void proj_kernel(
    const float* __restrict__ x, const short* __restrict__ WtF,
    const float* __restrict__ bq, const float* __restrict__ bk,
    const float* __restrict__ bv,
    short* __restrict__ qb, short* __restrict__ kF, short* __restrict__ vF) {
  int blk = blockIdx.x;
  int b  = blk >> 7;
  int r0 = (blk & 127) * 32;
  int t  = threadIdx.x;
  int w  = t >> 6;
  int l  = t & 63;
  int lc = l & 15;
  int q4 = l >> 4;

  __shared__ __align__(16) short sA[32][272];
  __shared__ __align__(16) short sV[256][40];
  __shared__ __align__(16) short sK[32][36];

  {
    const float* xb = x + (size_t)(b * N_ + r0) * C_;
#pragma unroll
    for (int ch = 0; ch < 8; ch++) {
      int f   = ch * 256 + t;
      int row = f >> 6;
      int col = (f & 63) * 4;
      float4v v = *(const float4v*)(xb + f * 4);
      short4v s;
      s[0] = f2bf_rne(v[0]); s[1] = f2bf_rne(v[1]);
      s[2] = f2bf_rne(v[2]); s[3] = f2bf_rne(v[3]);
      *(short4v*)(&sA[row][col]) = s;
    }
  }
  __syncthreads();

  float4v acc[10];
#pragma unroll
  for (int i = 0; i < 10; i++) { acc[i][0] = 0.f; acc[i][1] = 0.f; acc[i][2] = 0.f; acc[i][3] = 0.f; }

#pragma unroll
  for (int ks = 0; ks < 8; ks++) {
    short8 af0 = *(const short8*)(&sA[lc][ks * 32 + q4 * 8]);
    short8 af1 = *(const short8*)(&sA[16 + lc][ks * 32 + q4 * 8]);
#pragma unroll
    for (int nbo = 0; nbo < 5; nbo++) {
      int nb = nbo * 4 + w;
      short8 bf = *(const short8*)(WtF + (((nb << 3) + ks) << 9) + l * 8);
      acc[nbo * 2 + 0] = MFMA16(af0, bf, acc[nbo * 2 + 0], 0, 0, 0);
      acc[nbo * 2 + 1] = MFMA16(af1, bf, acc[nbo * 2 + 1], 0, 0, 0);
    }
  }

#pragma unroll
  for (int nbo = 0; nbo < 5; nbo++) {
    float bias;
    if (nbo == 0) bias = (w < 2) ? bq[w * 16 + lc] * LOG2E : bk[(w - 2) * 16 + lc];
    else          bias = bv[(nbo - 1) * 64 + w * 16 + lc];
#pragma unroll
    for (int rt = 0; rt < 2; rt++) {
#pragma unroll
      for (int r = 0; r < 4; r++) {
        int row = rt * 16 + q4 * 4 + r;
        short s = f2bf_rne(acc[nbo * 2 + rt][r] + bias);
        if (nbo == 0) {
          if (w < 2) qb[(size_t)(b * N_ + r0 + row) * D_ + w * 16 + lc] = s;
          else       sK[row][(w - 2) * 16 + lc] = s;
        } else {
          sV[(nbo - 1) * 64 + w * 16 + lc][row] = s;
        }
      }
    }
  }
  __syncthreads();

  int kt  = r0 >> 6;
  int ks0 = (r0 >> 5) & 1;

  {
    int c = t;
    size_t tb = ((size_t)(b * 64 + kt) * 32 + ks0 * 16 + (c >> 4)) * 512;
#pragma unroll
    for (int rg = 0; rg < 4; rg++) {
      short8 vv = *(const short8*)(&sV[c][rg * 8]);
      *(short8*)(vF + tb + (rg * 16 + (c & 15)) * 8) = vv;
    }
  }
  if (t < 128) {
    int row = t >> 2, dg = t & 3;
    size_t tb = ((size_t)(b * 64 + kt) * 4 + ks0 * 2 + (row >> 4)) * 512;
    short8 kv = *(const short8*)(&sK[row][dg * 8]);
    *(short8*)(kF + tb + (dg * 16 + (row & 15)) * 8) = kv;
  }
}

// ---------------------------------------------------------------------------
// Kernel 3a: flash partial. 512 blocks x 512 thr (2 blocks/CU).
// Block = (batch b, Q-tile qt 64 rows, kv-half hb). Wave w owns ALL 64
// q-rows x 32 channels (cb 2w, 2w+1) over the kv-half -> V read once, O
// complete per wave (NO end-of-kernel LDS merge). Waves 0-3 additionally
// produce QK+softmax for rowtile rq=w; they compute tile ti+1's sP while
// other waves run PV(ti) -> cross-wave pipeline, 1 barrier/tile.
// V double-buffered (named regs, const-indexed), K reloaded after use.
// Partial O stored fragment-linear (slot s = w*8+rt*2+cbo, one b64/acc).
// ---------------------------------------------------------------------------
__global__ __launch_bounds__(512, 4) void flash_partial_kernel(
    const short* __restrict__ qb, const short* __restrict__ kF,
    const short* __restrict__ vF, short* __restrict__ obuf,
    float* __restrict__ lbuf) {
  int blk = blockIdx.x;
  int b  = blk & 3;            // XCD (blk%8) <-> (b,hb): K/V-half L2-resident
  int hb = (blk >> 2) & 1;
  int qt = blk >> 3;
  int r0 = qt * 64;
  int t  = threadIdx.x;
  int w  = t >> 6;
  int l  = t & 63;
  int lc = l & 15;
  int q4 = l >> 4;
  int rq = w & 3;
  bool qkw = (w < 4);

  __shared__ __align__(16) short sP[2][64][72];  // 18.4 KB, [q][kv]

  int p = (b * 64 + qt) * 2 + hb;

  // Q as B-frag (n=q, k=d); log2e pre-folded
  short8 qf = *(const short8*)(qb + (size_t)(b * N_ + r0 + rq * 16 + lc) * D_ + q4 * 8);

  const short* kbp = kF + ((size_t)(b * 64 + hb * 32) * 4) * 512 + l * 8;
  const short* vbp = vF + ((size_t)(b * 64 + hb * 32) * 32 + 2 * w) * 512 + l * 8;
  // V frag (ti, ks, cbo) at: vbp + ti*16384 + ks*8192 + cbo*512

  short8 kC0, kC1, kC2, kC3;                       // K A-frags (current tile)
  short8 vX00, vX01, vX10, vX11;                   // V buf X [ks][cbo]
  short8 vY00, vY01, vY10, vY11;                   // V buf Y

  kC0 = *(const short8*)(kbp + 0);
  kC1 = *(const short8*)(kbp + 512);
  kC2 = *(const short8*)(kbp + 1024);
  kC3 = *(const short8*)(kbp + 1536);
  vX00 = *(const short8*)(vbp + 0);
  vX01 = *(const short8*)(vbp + 512);
  vX10 = *(const short8*)(vbp + 8192);
  vX11 = *(const short8*)(vbp + 8704);

  float4v O[8];  // [rt*2 + cbo]: 64 q x 32 ch
#pragma unroll
  for (int i = 0; i < 8; i++) { O[i][0] = 0.f; O[i][1] = 0.f; O[i][2] = 0.f; O[i][3] = 0.f; }
  float l_part = 0.f;

#define K_RELOAD(TI)                                                           \
  { size_t o_ = (size_t)(TI) * 2048;                                           \
    kC0 = *(const short8*)(kbp + o_);                                          \
    kC1 = *(const short8*)(kbp + o_ + 512);                                    \
    kC2 = *(const short8*)(kbp + o_ + 1024);                                   \
    kC3 = *(const short8*)(kbp + o_ + 1536); }

#define QK_STEP(SPB, VALID)                                                    \
  { float4v z; z[0] = 0.f; z[1] = 0.f; z[2] = 0.f; z[3] = 0.f;                 \
    float4v S0 = MFMA16(kC0, qf, z, 0, 0, 0);                                  \
    float4v S1 = MFMA16(kC1, qf, z, 0, 0, 0);                                  \
    float4v S2 = MFMA16(kC2, qf, z, 0, 0, 0);                                  \
    float4v S3 = MFMA16(kC3, qf, z, 0, 0, 0);                                  \
    short* rowp = &sP[SPB][rq * 16 + lc][q4 * 4];                              \
    float ts = 0.f;                                                            \
    { float p0 = fast_exp2(S0[0]), p1 = fast_exp2(S0[1]);                      \
      float p2 = fast_exp2(S0[2]), p3 = fast_exp2(S0[3]);                      \
      ts += (p0 + p1) + (p2 + p3);                                             \
      short4v pk; pk[0] = f2bf_rne(p0); pk[1] = f2bf_rne(p1);                  \
      pk[2] = f2bf_rne(p2); pk[3] = f2bf_rne(p3);                              \
      *(short4v*)(rowp + 0) = pk; }                                            \
    { float p0 = fast_exp2(S1[0]), p1 = fast_exp2(S1[1]);                      \
      float p2 = fast_exp2(S1[2]), p3 = fast_exp2(S1[3]);                      \
      ts += (p0 + p1) + (p2 + p3);                                             \
      short4v pk; pk[0] = f2bf_rne(p0); pk[1] = f2bf_rne(p1);                  \
      pk[2] = f2bf_rne(p2); pk[3] = f2bf_rne(p3);                              \
      *(short4v*)(rowp + 16) = pk; }                                           \
    { float p0 = fast_exp2(S2[0]), p1 = fast_exp2(S2[1]);                      \
      float p2 = fast_exp2(S2[2]), p3 = fast_exp2(S2[3]);                      \
      ts += (p0 + p1) + (p2 + p3);                                             \
      short4v pk; pk[0] = f2bf_rne(p0); pk[1] = f2bf_rne(p1);                  \
      pk[2] = f2bf_rne(p2); pk[3] = f2bf_rne(p3);                              \
      *(short4v*)(rowp + 32) = pk; }                                           \
    { float p0 = fast_exp2(S3[0]), p1 = fast_exp2(S3[1]);                      \
      float p2 = fast_exp2(S3[2]), p3 = fast_exp2(S3[3]);                      \
      ts += (p0 + p1) + (p2 + p3);                                             \
      short4v pk; pk[0] = f2bf_rne(p0); pk[1] = f2bf_rne(p1);                  \
      pk[2] = f2bf_rne(p2); pk[3] = f2bf_rne(p3);                              \
      *(short4v*)(rowp + 48) = pk; }                                           \
    if (VALID) l_part += ts; }

#define PV_STEP(SPB, V00, V01, V10, V11)                                       \
  { _Pragma("unroll")                                                          \
    for (int rt = 0; rt < 4; rt++) {                                           \
      short8 pf0 = *(const short8*)(&sP[SPB][rt * 16 + lc][q4 * 8]);           \
      short8 pf1 = *(const short8*)(&sP[SPB][rt * 16 + lc][32 + q4 * 8]);      \
      O[rt * 2 + 0] = MFMA16(pf0, V00, O[rt * 2 + 0], 0, 0, 0);                \
      O[rt * 2 + 0] = MFMA16(pf1, V10, O[rt * 2 + 0], 0, 0, 0);                \
      O[rt * 2 + 1] = MFMA16(pf0, V01, O[rt * 2 + 1], 0, 0, 0);                \
      O[rt * 2 + 1] = MFMA16(pf1, V11, O[rt * 2 + 1], 0, 0, 0);                \
    } }

  // preloop: QK(0) -> sP[0]; K(1) staged
  if (qkw) {
    QK_STEP(0, true)
    K_RELOAD(1)
  }
  __syncthreads();

  for (int ti = 0; ti < 32; ti += 2) {
    int n1 = ti + 1;
    int n2 = (ti + 2 < 32) ? ti + 2 : 31;
    bool v2 = (ti + 2 < 32);
    int n3 = (ti + 3 < 32) ? ti + 3 : 31;

    // ---- half A: QK(n1) -> sP[1] (qk waves) || PV(ti) from sP[0] (all) ----
    { size_t vo = (size_t)n1 * 16384;
      vY00 = *(const short8*)(vbp + vo);
      vY01 = *(const short8*)(vbp + vo + 512);
      vY10 = *(const short8*)(vbp + vo + 8192);
      vY11 = *(const short8*)(vbp + vo + 8704); }
    if (qkw) {
      QK_STEP(1, true)     // uses kC = K(n1)
      K_RELOAD(n2)
    }
    PV_STEP(0, vX00, vX01, vX10, vX11)
    __syncthreads();

    // ---- half B: QK(n2) -> sP[0] (qk waves) || PV(n1) from sP[1] (all) ----
    { size_t vo = (size_t)n2 * 16384;
      vX00 = *(const short8*)(vbp + vo);
      vX01 = *(const short8*)(vbp + vo + 512);
      vX10 = *(const short8*)(vbp + vo + 8192);
      vX11 = *(const short8*)(vbp + vo + 8704); }
    if (qkw) {
      QK_STEP(0, v2)       // uses kC = K(n2); clamped tail doesn't recount l
      K_RELOAD(n3)
    }
    PV_STEP(1, vY00, vY01, vY10, vY11)
    __syncthreads();
  }
#undef K_RELOAD
#undef QK_STEP
#undef PV_STEP

  // ---- store O partials fragment-linear: slot s = w*8 + rt*2 + cbo ----
  {
    short* ob = obuf + ((size_t)p * 64 + w * 8) * 256 + l * 4;
#pragma unroll
    for (int a = 0; a < 8; a++) {
      float4v o = O[a];
      short4v pk;
      pk[0] = f2bf_rne(o[0]); pk[1] = f2bf_rne(o[1]);
      pk[2] = f2bf_rne(o[2]); pk[3] = f2bf_rne(o[3]);
      *(short4v*)(ob + a * 256) = pk;
    }
  }
  if (qkw) {
    float l_tot = l_part + __shfl_xor(l_part, 16, 64);
    l_tot += __shfl_xor(l_tot, 32, 64);
    if (q4 == 0) lbuf[(size_t)p * 64 + rq * 16 + lc] = l_tot;
  }
}

// ---------------------------------------------------------------------------
// Kernel 3b: merge the two kv-half partials, normalize, gamma*attn + x.
// 256 blocks x 256 thr. Thread t = (slot s = t>>2, quarter qr = t&3):
// reads 128 B coalesced from each partial, writes 4 x 64 B output rows.
// slot decode: w=s>>3, j=s&7, rt=j>>1, cbo=j&1; q=rt*16+qr*4+r,
// ch=w*32+cbo*16+i (i = lane&15 position inside the 16-ch group).
// ---------------------------------------------------------------------------
__global__ __launch_bounds__(256) void merge_kernel(
    const short* __restrict__ obuf, const float* __restrict__ lbuf,
    const float* __restrict__ xin, const float* __restrict__ gptr,
    float* __restrict__ out) {
  int blk = blockIdx.x;   // = b*64 + qt
  int t   = threadIdx.x;
  int s   = t >> 2;
  int qr  = t & 3;
  int wv  = s >> 3, j = s & 7, rt = j >> 1, cbo = j & 1;
  int chb = wv * 32 + cbo * 16;
  float g = *gptr;

  const short* o0 = obuf + ((size_t)(blk * 2 + 0) * 64 + s) * 256 + qr * 64;
  const short* o1 = obuf + ((size_t)(blk * 2 + 1) * 64 + s) * 256 + qr * 64;
  const float* l0 = lbuf + (size_t)(blk * 2 + 0) * 64;
  const float* l1 = lbuf + (size_t)(blk * 2 + 1) * 64;

  short4v a[16], c[16];
#pragma unroll
  for (int i = 0; i < 16; i++) {
    a[i] = ((const short4v*)o0)[i];
    c[i] = ((const short4v*)o1)[i];
  }

  size_t rowbase = (size_t)blk * 64;
#pragma unroll
  for (int r = 0; r < 4; r++) {
    int q = rt * 16 + qr * 4 + r;
    float linv = __builtin_amdgcn_rcpf(l0[q] + l1[q]);
    size_t gi = (rowbase + q) * C_ + chb;
#pragma unroll
    for (int i0 = 0; i0 < 16; i0 += 4) {
      float4v xv = *(const float4v*)(xin + gi + i0);
      float4v ov;
#pragma unroll
      for (int e = 0; e < 4; e++)
        ov[e] = g * ((bf2f(a[i0 + e][r]) + bf2f(c[i0 + e][r])) * linv) + xv[e];
      *(float4v*)(out + gi + i0) = ov;
    }
  }
}

// ---------------------------------------------------------------------------
extern "C" void kernel_launch(void* const* d_in, const int* in_sizes, int n_in,
                              void* d_out, int out_size, void* d_ws, size_t ws_size,
                              hipStream_t stream) {
  const float* x     = (const float*)d_in[0];
  const float* Wq    = (const float*)d_in[1];
  const float* bq    = (const float*)d_in[2];
  const float* Wk    = (const float*)d_in[3];
  const float* bk    = (const float*)d_in[4];
  const float* Wv    = (const float*)d_in[5];
  const float* bv    = (const float*)d_in[6];
  const float* gamma = (const float*)d_in[7];
  float* out = (float*)d_out;

  char* ws = (char*)d_ws;
  short* qb   = (short*)ws;                   // 1 MB   row-major [N][32]
  short* kF   = (short*)(ws + (1u << 20));    // 1 MB   fragment-linear
  short* vF   = (short*)(ws + (2u << 20));    // 8 MB   fragment-linear
  short* WtF  = (short*)(ws + (10u << 20));   // 160 KB fragment-linear
  short* obuf = (short*)(ws + (11u << 20));   // 16 MB  bf16 partial O (slot layout)
  float* lbuf = (float*)(ws + (28u << 20));   // 128 KB fp32 partial l [512][64]

  hipLaunchKernelGGL(cast_w_kernel,        dim3(320), dim3(256), 0, stream, Wq, Wk, Wv, WtF);
  hipLaunchKernelGGL(proj_kernel,          dim3(512), dim3(256), 0, stream, x, WtF, bq, bk, bv, qb, kF, vF);
  hipLaunchKernelGGL(flash_partial_kernel, dim3(512), dim3(512), 0, stream, qb, kF, vF, obuf, lbuf);
  hipLaunchKernelGGL(merge_kernel,         dim3(256), dim3(256), 0, stream, obuf, lbuf, x, gamma, out);
}